// Round 1
// baseline (584.483 us; speedup 1.0000x reference)
//
#include <hip/hip_runtime.h>
#include <hip/hip_bf16.h>
#include <stdint.h>

#define NB 1024          // B molecules
#define LMAX 160
#define DIM 128
#define NH 4
#define HDIM 32
#define ATT_SCALE 0.1767766952966369f   // 32^-0.5
#define LN_EPS 1e-5f

__device__ __forceinline__ float bflo(uint32_t u) { return __uint_as_float(u << 16); }
__device__ __forceinline__ float bfhi(uint32_t u) { return __uint_as_float(u & 0xffff0000u); }
__device__ __forceinline__ ushort f2bf(float f) {
    uint32_t x = __float_as_uint(f);
    x += 0x7fffu + ((x >> 16) & 1u);   // round-to-nearest-even
    return (ushort)(x >> 16);
}

// ---------------------------------------------------------------------------
// K0: segment starts/counts via binary search on the sorted batch arrays.
// starts/counts layout: [side*NB + b], side 0 = don, 1 = acc.
// ---------------------------------------------------------------------------
__global__ void seg_kernel(const int* __restrict__ bd, const int* __restrict__ ba,
                           int* __restrict__ starts, int* __restrict__ counts, int N)
{
    int t = blockIdx.x * blockDim.x + threadIdx.x;
    if (t >= 2 * NB) return;
    int side = t >> 10;
    int b = t & (NB - 1);
    const int* arr = side ? ba : bd;
    int lo = 0, hi = N;
    while (lo < hi) { int mid = (lo + hi) >> 1; if (arr[mid] < b) lo = mid + 1; else hi = mid; }
    int st = lo;
    hi = N;
    while (lo < hi) { int mid = (lo + hi) >> 1; if (arr[mid] < b + 1) lo = mid + 1; else hi = mid; }
    starts[t] = st;
    counts[t] = lo - st;
}

// ---------------------------------------------------------------------------
// K1: projections.  out[rz] = x_side @ W + b  (rz = side*3 + {q,k,v}), bf16 out.
// 64 rows x 64 cols per block, 4x4 register blocking, fp32.
// ---------------------------------------------------------------------------
__global__ __launch_bounds__(256) void proj_kernel(
    const float* __restrict__ x_don, const float* __restrict__ x_acc,
    const float* __restrict__ Wq, const float* __restrict__ bq,
    const float* __restrict__ Wk, const float* __restrict__ bk,
    const float* __restrict__ Wv, const float* __restrict__ bv,
    ushort* __restrict__ qkv, int N)
{
    __shared__ float xs[64][132];   // +4 pad: keeps reads 2-way (free), 16B-aligned rows
    __shared__ float ws[128][64];   // W[k][c] k-major -> b128 col reads conflict-free
    const int rz = blockIdx.z;
    const int side = rz / 3, wk = rz % 3;
    const float* x    = side ? x_acc : x_don;
    const float* W    = (wk == 0) ? Wq : (wk == 1) ? Wk : Wv;
    const float* bias = (wk == 0) ? bq : (wk == 1) ? bk : bv;
    ushort* out = qkv + (size_t)rz * N * DIM;
    const int r0 = blockIdx.x * 64;
    const int c0 = blockIdx.y * 64;
    const int t = threadIdx.x;

    #pragma unroll
    for (int p = 0; p < 8; ++p) {                 // 64x128 x-tile
        int lin = (p * 256 + t) * 4;
        int r = lin >> 7, k = lin & 127;
        *reinterpret_cast<float4*>(&xs[r][k]) =
            *reinterpret_cast<const float4*>(&x[((size_t)(r0 + r) << 7) + k]);
    }
    #pragma unroll
    for (int p = 0; p < 8; ++p) {                 // 128x64 W-tile
        int lin = (p * 256 + t) * 4;
        int k = lin >> 6, c = lin & 63;
        *reinterpret_cast<float4*>(&ws[k][c]) =
            *reinterpret_cast<const float4*>(&W[((size_t)k << 7) + c0 + c]);
    }
    __syncthreads();

    const int tx = t & 15, ty = t >> 4;
    float acc[4][4] = {};
    #pragma unroll 4
    for (int k = 0; k < 128; ++k) {
        float4 w4 = *reinterpret_cast<const float4*>(&ws[k][tx * 4]);
        #pragma unroll
        for (int i = 0; i < 4; ++i) {
            float xv = xs[ty * 4 + i][k];
            acc[i][0] = fmaf(xv, w4.x, acc[i][0]);
            acc[i][1] = fmaf(xv, w4.y, acc[i][1]);
            acc[i][2] = fmaf(xv, w4.z, acc[i][2]);
            acc[i][3] = fmaf(xv, w4.w, acc[i][3]);
        }
    }

    #pragma unroll
    for (int i = 0; i < 4; ++i) {
        int r = r0 + ty * 4 + i;
        int c = c0 + tx * 4;
        ushort u0 = f2bf(acc[i][0] + bias[c + 0]);
        ushort u1 = f2bf(acc[i][1] + bias[c + 1]);
        ushort u2 = f2bf(acc[i][2] + bias[c + 2]);
        ushort u3 = f2bf(acc[i][3] + bias[c + 3]);
        uint2 pk;
        pk.x = (uint32_t)u0 | ((uint32_t)u1 << 16);
        pk.y = (uint32_t)u2 | ((uint32_t)u3 << 16);
        *reinterpret_cast<uint2*>(&out[((size_t)r << 7) + c]) = pk;
    }
}

// ---------------------------------------------------------------------------
// K2: per-molecule cross attention.  grid (B, 2).  dir0: Q=don, KV=acc (-> out rows [0,N))
// K/V staged in LDS as bf16 (80KB).  Each thread owns one (q,h) pair, 2-pass softmax.
// Writes "attended" (pre-Wo) fp32 into d_out rows.
// ---------------------------------------------------------------------------
__global__ __launch_bounds__(256) void attn_kernel(
    const ushort* __restrict__ qkv,
    const int* __restrict__ starts, const int* __restrict__ counts,
    float* __restrict__ out, int N)
{
    __shared__ ushort Ks[LMAX][DIM];
    __shared__ ushort Vs[LMAX][DIM];
    const int b = blockIdx.x;
    const int dir = blockIdx.y;
    const int qside = dir, kside = 1 - dir;
    const int qs = starts[qside * NB + b];
    const int nq = counts[qside * NB + b];
    if (nq == 0) return;
    const int kst = starts[kside * NB + b];
    const int nk = min(counts[kside * NB + b], LMAX);
    const ushort* Q = qkv + (size_t)(qside * 3 + 0) * N * DIM;
    const ushort* K = qkv + (size_t)(kside * 3 + 1) * N * DIM;
    const ushort* V = qkv + (size_t)(kside * 3 + 2) * N * DIM;
    const int t = threadIdx.x;

    for (int i = t; i < nk * 16; i += 256) {      // 16B chunks, coalesced
        int r = i >> 4, c = (i & 15) << 3;
        *reinterpret_cast<uint4*>(&Ks[r][c]) =
            *reinterpret_cast<const uint4*>(&K[((size_t)(kst + r) << 7) + c]);
        *reinterpret_cast<uint4*>(&Vs[r][c]) =
            *reinterpret_cast<const uint4*>(&V[((size_t)(kst + r) << 7) + c]);
    }
    __syncthreads();

    for (int p = t; p < nq * NH; p += 256) {
        const int q = p >> 2, h = p & 3;
        float qf[32];
        const uint32_t* qrow =
            reinterpret_cast<const uint32_t*>(&Q[((size_t)(qs + q) << 7) + h * HDIM]);
        #pragma unroll
        for (int j = 0; j < 16; ++j) {
            uint32_t u = qrow[j];
            qf[2 * j]     = bflo(u);
            qf[2 * j + 1] = bfhi(u);
        }
        // pass 1: row max
        float m = -1e30f;
        for (int k = 0; k < nk; ++k) {
            const uint32_t* kr = reinterpret_cast<const uint32_t*>(&Ks[k][h * HDIM]);
            float s = 0.f;
            #pragma unroll
            for (int j = 0; j < 16; ++j) {
                uint32_t u = kr[j];
                s = fmaf(qf[2 * j], bflo(u), s);
                s = fmaf(qf[2 * j + 1], bfhi(u), s);
            }
            m = fmaxf(m, s * ATT_SCALE);
        }
        // pass 2: exp + accumulate
        float l = 0.f;
        float o[32];
        #pragma unroll
        for (int j = 0; j < 32; ++j) o[j] = 0.f;
        for (int k = 0; k < nk; ++k) {
            const uint32_t* kr = reinterpret_cast<const uint32_t*>(&Ks[k][h * HDIM]);
            float s = 0.f;
            #pragma unroll
            for (int j = 0; j < 16; ++j) {
                uint32_t u = kr[j];
                s = fmaf(qf[2 * j], bflo(u), s);
                s = fmaf(qf[2 * j + 1], bfhi(u), s);
            }
            float e = __expf(fmaf(s, ATT_SCALE, -m));
            l += e;
            const uint32_t* vr = reinterpret_cast<const uint32_t*>(&Vs[k][h * HDIM]);
            #pragma unroll
            for (int j = 0; j < 16; ++j) {
                uint32_t u = vr[j];
                o[2 * j]     = fmaf(e, bflo(u), o[2 * j]);
                o[2 * j + 1] = fmaf(e, bfhi(u), o[2 * j + 1]);
            }
        }
        const float inv = 1.f / fmaxf(l, 1e-9f);
        float* orow = &out[((size_t)(dir * N + qs + q) << 7) + h * HDIM];
        #pragma unroll
        for (int j4 = 0; j4 < 8; ++j4) {
            float4 v = make_float4(o[4 * j4] * inv, o[4 * j4 + 1] * inv,
                                   o[4 * j4 + 2] * inv, o[4 * j4 + 3] * inv);
            *reinterpret_cast<float4*>(&orow[4 * j4]) = v;
        }
    }
}

// ---------------------------------------------------------------------------
// K3: y = attended @ Wo + bo + x_residual; out = LayerNorm(y).  64 rows/block,
// full 128 cols so LN stays in-block (16-lane shuffle reduce).  Reads attended
// from d_out and overwrites the same rows.
// ---------------------------------------------------------------------------
__global__ __launch_bounds__(256) void out_kernel(
    const float* __restrict__ x_don, const float* __restrict__ x_acc,
    const float* __restrict__ Wo, const float* __restrict__ bo,
    const float* __restrict__ ln_g, const float* __restrict__ ln_b,
    float* __restrict__ out, int N)
{
    __shared__ float xs[64][132];
    __shared__ float ws[128][128];
    const int t = threadIdx.x;
    const int r0 = blockIdx.x * 64;

    #pragma unroll
    for (int p = 0; p < 16; ++p) {
        int lin = (p * 256 + t) * 4;
        *reinterpret_cast<float4*>(((float*)ws) + lin) =
            *reinterpret_cast<const float4*>(Wo + lin);
    }
    #pragma unroll
    for (int p = 0; p < 8; ++p) {
        int lin = (p * 256 + t) * 4;
        int r = lin >> 7, k = lin & 127;
        *reinterpret_cast<float4*>(&xs[r][k]) =
            *reinterpret_cast<const float4*>(&out[((size_t)(r0 + r) << 7) + k]);
    }
    __syncthreads();

    const int tx = t & 15, ty = t >> 4;
    float acc[4][8] = {};                 // 4 rows x (cols 4tx..+3 and 64+4tx..+3)
    #pragma unroll 2
    for (int k = 0; k < 128; ++k) {
        float4 wa = *reinterpret_cast<const float4*>(&ws[k][tx * 4]);
        float4 wb = *reinterpret_cast<const float4*>(&ws[k][64 + tx * 4]);
        #pragma unroll
        for (int i = 0; i < 4; ++i) {
            float xv = xs[ty * 4 + i][k];
            acc[i][0] = fmaf(xv, wa.x, acc[i][0]);
            acc[i][1] = fmaf(xv, wa.y, acc[i][1]);
            acc[i][2] = fmaf(xv, wa.z, acc[i][2]);
            acc[i][3] = fmaf(xv, wa.w, acc[i][3]);
            acc[i][4] = fmaf(xv, wb.x, acc[i][4]);
            acc[i][5] = fmaf(xv, wb.y, acc[i][5]);
            acc[i][6] = fmaf(xv, wb.z, acc[i][6]);
            acc[i][7] = fmaf(xv, wb.w, acc[i][7]);
        }
    }

    #pragma unroll
    for (int i = 0; i < 4; ++i) {
        int gr = r0 + ty * 4 + i;
        const float* xres = (gr < N) ? &x_don[(size_t)gr << 7]
                                     : &x_acc[(size_t)(gr - N) << 7];
        float y[8];
        float s = 0.f, ss = 0.f;
        #pragma unroll
        for (int j = 0; j < 4; ++j) {
            int c = tx * 4 + j;
            y[j] = acc[i][j] + bo[c] + xres[c];
            s += y[j]; ss += y[j] * y[j];
        }
        #pragma unroll
        for (int j = 0; j < 4; ++j) {
            int c = 64 + tx * 4 + j;
            y[4 + j] = acc[i][4 + j] + bo[c] + xres[c];
            s += y[4 + j]; ss += y[4 + j] * y[4 + j];
        }
        #pragma unroll
        for (int mk = 1; mk < 16; mk <<= 1) {   // reduce across the 16 tx lanes
            s  += __shfl_xor(s, mk);
            ss += __shfl_xor(ss, mk);
        }
        float mu   = s * (1.f / 128.f);
        float var  = ss * (1.f / 128.f) - mu * mu;
        float rinv = rsqrtf(var + LN_EPS);
        float4 oa, ob;
        {
            int c = tx * 4;
            oa.x = (y[0] - mu) * rinv * ln_g[c + 0] + ln_b[c + 0];
            oa.y = (y[1] - mu) * rinv * ln_g[c + 1] + ln_b[c + 1];
            oa.z = (y[2] - mu) * rinv * ln_g[c + 2] + ln_b[c + 2];
            oa.w = (y[3] - mu) * rinv * ln_g[c + 3] + ln_b[c + 3];
            int c2 = 64 + tx * 4;
            ob.x = (y[4] - mu) * rinv * ln_g[c2 + 0] + ln_b[c2 + 0];
            ob.y = (y[5] - mu) * rinv * ln_g[c2 + 1] + ln_b[c2 + 1];
            ob.z = (y[6] - mu) * rinv * ln_g[c2 + 2] + ln_b[c2 + 2];
            ob.w = (y[7] - mu) * rinv * ln_g[c2 + 3] + ln_b[c2 + 3];
        }
        *reinterpret_cast<float4*>(&out[((size_t)gr << 7) + tx * 4]) = oa;
        *reinterpret_cast<float4*>(&out[((size_t)gr << 7) + 64 + tx * 4]) = ob;
    }
}

// ---------------------------------------------------------------------------
extern "C" void kernel_launch(void* const* d_in, const int* in_sizes, int n_in,
                              void* d_out, int out_size, void* d_ws, size_t ws_size,
                              hipStream_t stream)
{
    const float* x_don = (const float*)d_in[0];
    const float* x_acc = (const float*)d_in[1];
    const float* Wq = (const float*)d_in[2];  const float* bq = (const float*)d_in[3];
    const float* Wk = (const float*)d_in[4];  const float* bk = (const float*)d_in[5];
    const float* Wv = (const float*)d_in[6];  const float* bv = (const float*)d_in[7];
    const float* Wo = (const float*)d_in[8];  const float* bo = (const float*)d_in[9];
    const float* ln_g = (const float*)d_in[10]; const float* ln_b = (const float*)d_in[11];
    const int* batch_don = (const int*)d_in[12];
    const int* batch_acc = (const int*)d_in[13];
    const int N = in_sizes[0] / DIM;          // 65536
    float* out = (float*)d_out;

    char* ws = (char*)d_ws;
    int* starts = (int*)ws;                   // 2*NB ints
    int* counts = starts + 2 * NB;            // 2*NB ints
    ushort* qkv = (ushort*)(ws + 16384);      // 6 arrays of N*DIM bf16 (96MB)

    seg_kernel<<<(2 * NB + 255) / 256, 256, 0, stream>>>(batch_don, batch_acc, starts, counts, N);

    dim3 gproj(N / 64, 2, 6);
    proj_kernel<<<gproj, 256, 0, stream>>>(x_don, x_acc, Wq, bq, Wk, bk, Wv, bv, qkv, N);

    dim3 gattn(NB, 2);
    attn_kernel<<<gattn, 256, 0, stream>>>(qkv, starts, counts, out, N);

    out_kernel<<<(2 * N) / 64, 256, 0, stream>>>(x_don, x_acc, Wo, bo, ln_g, ln_b, out, N);
}

// Round 2
// 291.782 us; speedup vs baseline: 2.0031x; 2.0031x over previous
//
#include <hip/hip_runtime.h>
#include <stdint.h>

#define NB 1024          // B molecules
#define LMAX 160
#define DIM 128
#define NH 4
#define HDIM 32
#define ATT_SCALE 0.1767766952966369f   // 32^-0.5
#define LN_EPS 1e-5f

typedef __attribute__((ext_vector_type(8))) short bf16x8;
typedef __attribute__((ext_vector_type(4))) float f32x4;

__device__ __forceinline__ float bflo(uint32_t u) { return __uint_as_float(u << 16); }
__device__ __forceinline__ float bfhi(uint32_t u) { return __uint_as_float(u & 0xffff0000u); }
__device__ __forceinline__ ushort f2bf(float f) {
    uint32_t x = __float_as_uint(f);
    x += 0x7fffu + ((x >> 16) & 1u);   // round-to-nearest-even
    return (ushort)(x >> 16);
}

// ---------------------------------------------------------------------------
// K0: segment starts/counts via binary search on the sorted batch arrays.
// ---------------------------------------------------------------------------
__global__ void seg_kernel(const int* __restrict__ bd, const int* __restrict__ ba,
                           int* __restrict__ starts, int* __restrict__ counts, int N)
{
    int t = blockIdx.x * blockDim.x + threadIdx.x;
    if (t >= 2 * NB) return;
    int side = t >> 10;
    int b = t & (NB - 1);
    const int* arr = side ? ba : bd;
    int lo = 0, hi = N;
    while (lo < hi) { int mid = (lo + hi) >> 1; if (arr[mid] < b) lo = mid + 1; else hi = mid; }
    int st = lo;
    hi = N;
    while (lo < hi) { int mid = (lo + hi) >> 1; if (arr[mid] < b + 1) lo = mid + 1; else hi = mid; }
    starts[t] = st;
    counts[t] = lo - st;
}

// ---------------------------------------------------------------------------
// K0b: pre-transpose weights to bf16 [c][k] layout (B-fragment-friendly).
// wtg[m][c][k], m: 0=Wq 1=Wk 2=Wv 3=Wo.  Runs once per launch, tiny.
// ---------------------------------------------------------------------------
__global__ void prep_kernel(const float* __restrict__ Wq, const float* __restrict__ Wk,
                            const float* __restrict__ Wv, const float* __restrict__ Wo,
                            ushort* __restrict__ wtg)
{
    int t = blockIdx.x * blockDim.x + threadIdx.x;   // 65536 threads
    int m = t >> 14;
    int idx = t & 16383;
    int k = idx >> 7, c = idx & 127;
    const float* W = (m == 0) ? Wq : (m == 1) ? Wk : (m == 2) ? Wv : Wo;
    wtg[(m << 14) + c * DIM + k] = f2bf(W[idx]);     // read coalesced, write strided (tiny)
}

// ---------------------------------------------------------------------------
// K1: MFMA projections.  Per block: 128 rows x 128 cols, K=128, loop Wq/Wk/Wv.
// xs: x tile bf16 [128][136] (pad -> 2-way banks, free).  wt: W^T tile [c][k].
// 4 waves, each 32 rows; acc[2][8] f32x4; 16x16x32 bf16 MFMA.
// ---------------------------------------------------------------------------
__global__ __launch_bounds__(256) void proj_mfma(
    const float* __restrict__ x_don, const float* __restrict__ x_acc,
    const ushort* __restrict__ wtg,
    const float* __restrict__ bq, const float* __restrict__ bk, const float* __restrict__ bv,
    ushort* __restrict__ qkv, int N)
{
    __shared__ ushort xs[128][136];
    __shared__ ushort wt[128][136];
    const int side = blockIdx.y;
    const float* x = side ? x_acc : x_don;
    const int r0 = blockIdx.x * 128;
    const int t = threadIdx.x;
    const int lane = t & 63, wid = t >> 6;
    const int r16 = lane & 15, kg = lane >> 4;

    #pragma unroll
    for (int p = 0; p < 16; ++p) {                   // stage x (fp32 -> bf16)
        int lin = (p * 256 + t) * 4;
        int r = lin >> 7, k = lin & 127;
        float4 v = *reinterpret_cast<const float4*>(&x[(size_t)(r0 + r) * DIM + k]);
        uint2 pk;
        pk.x = (uint32_t)f2bf(v.x) | ((uint32_t)f2bf(v.y) << 16);
        pk.y = (uint32_t)f2bf(v.z) | ((uint32_t)f2bf(v.w) << 16);
        *reinterpret_cast<uint2*>(&xs[r][k]) = pk;
    }

    for (int w = 0; w < 3; ++w) {
        __syncthreads();                             // xs ready / prior-wt reads done
        const ushort* wsrc = wtg + ((size_t)(side ? w : w) << 14) + (w << 14) - (w << 14) + (w << 14);
        wsrc = wtg + ((size_t)w << 14);              // Wq/Wk/Wv shared by both sides
        #pragma unroll
        for (int p = 0; p < 8; ++p) {
            int lin = (p * 256 + t) * 8;
            int c = lin >> 7, k = lin & 127;
            *reinterpret_cast<uint4*>(&wt[c][k]) =
                *reinterpret_cast<const uint4*>(&wsrc[c * DIM + k]);
        }
        __syncthreads();

        f32x4 acc[2][8];
        #pragma unroll
        for (int i = 0; i < 2; ++i)
            #pragma unroll
            for (int j = 0; j < 8; ++j) acc[i][j] = (f32x4){0.f, 0.f, 0.f, 0.f};

        #pragma unroll
        for (int ks = 0; ks < 4; ++ks) {
            int kb = ks * 32 + kg * 8;
            bf16x8 a0 = *reinterpret_cast<const bf16x8*>(&xs[wid * 32 + r16][kb]);
            bf16x8 a1 = *reinterpret_cast<const bf16x8*>(&xs[wid * 32 + 16 + r16][kb]);
            #pragma unroll
            for (int ct = 0; ct < 8; ++ct) {
                bf16x8 bfr = *reinterpret_cast<const bf16x8*>(&wt[ct * 16 + r16][kb]);
                acc[0][ct] = __builtin_amdgcn_mfma_f32_16x16x32_bf16(a0, bfr, acc[0][ct], 0, 0, 0);
                acc[1][ct] = __builtin_amdgcn_mfma_f32_16x16x32_bf16(a1, bfr, acc[1][ct], 0, 0, 0);
            }
        }

        const float* bias = (w == 0) ? bq : (w == 1) ? bk : bv;
        float b8[8];
        #pragma unroll
        for (int ct = 0; ct < 8; ++ct) b8[ct] = bias[ct * 16 + r16];
        ushort* outp = qkv + (size_t)(side * 3 + w) * N * DIM;
        #pragma unroll
        for (int rt = 0; rt < 2; ++rt)
            #pragma unroll
            for (int ct = 0; ct < 8; ++ct)
                #pragma unroll
                for (int j = 0; j < 4; ++j) {
                    int rr = r0 + wid * 32 + rt * 16 + kg * 4 + j;   // D: row=(lane>>4)*4+reg
                    outp[(size_t)rr * DIM + ct * 16 + r16] = f2bf(acc[rt][ct][j] + b8[ct]);
                }
    }
}

// ---------------------------------------------------------------------------
// K2: per-molecule cross attention, ONE-pass online softmax (defer-max THR=8).
// K staged in LDS (40KB -> 4 blocks/CU); V read from global (wave-broadcast,
// L1/L2-served).  Attended written bf16 IN PLACE over the Q slot (each (q,h)
// pair owns its 64B slice exclusively).
// ---------------------------------------------------------------------------
__global__ __launch_bounds__(256, 4) void attn_kernel(
    ushort* __restrict__ qkv,
    const int* __restrict__ starts, const int* __restrict__ counts, int N)
{
    __shared__ ushort Ks[LMAX][DIM];
    const int b = blockIdx.x;
    const int dir = blockIdx.y;
    const int qside = dir, kside = 1 - dir;
    const int qs = starts[qside * NB + b];
    const int nq = counts[qside * NB + b];
    if (nq == 0) return;
    const int kst = starts[kside * NB + b];
    const int nk = min(counts[kside * NB + b], LMAX);
    ushort* Q = qkv + (size_t)(qside * 3) * N * DIM;
    const ushort* K = qkv + (size_t)(kside * 3 + 1) * N * DIM;
    const ushort* V = qkv + (size_t)(kside * 3 + 2) * N * DIM;
    const int t = threadIdx.x;

    for (int i = t; i < nk * 16; i += 256) {
        int r = i >> 4, c = (i & 15) << 3;
        *reinterpret_cast<uint4*>(&Ks[r][c]) =
            *reinterpret_cast<const uint4*>(&K[((size_t)(kst + r)) * DIM + c]);
    }
    __syncthreads();

    for (int p = t; p < nq * NH; p += 256) {
        const int q = p >> 2, h = p & 3;
        ushort* qrow = Q + (size_t)(qs + q) * DIM + h * HDIM;
        float qf[32];
        #pragma unroll
        for (int jj = 0; jj < 4; ++jj) {
            uint4 u4 = *reinterpret_cast<const uint4*>(qrow + jj * 8);
            uint32_t uu[4] = {u4.x, u4.y, u4.z, u4.w};
            #pragma unroll
            for (int j2 = 0; j2 < 4; ++j2) {
                qf[jj * 8 + 2 * j2]     = bflo(uu[j2]);
                qf[jj * 8 + 2 * j2 + 1] = bfhi(uu[j2]);
            }
        }
        const ushort* Vb = V + (size_t)kst * DIM + h * HDIM;
        float m = -1e30f, l = 0.f;
        float o[32];
        #pragma unroll
        for (int j = 0; j < 32; ++j) o[j] = 0.f;

        for (int k = 0; k < nk; ++k) {
            const uint32_t* kr = reinterpret_cast<const uint32_t*>(&Ks[k][h * HDIM]);
            float s = 0.f;
            #pragma unroll
            for (int j = 0; j < 16; ++j) {
                uint32_t u = kr[j];
                s = fmaf(qf[2 * j], bflo(u), s);
                s = fmaf(qf[2 * j + 1], bfhi(u), s);
            }
            s *= ATT_SCALE;
            if (__builtin_expect(s > m + 8.f, 0)) {  // defer-max rescale (T13)
                float corr = __expf(m - s);
                l *= corr;
                #pragma unroll
                for (int j = 0; j < 32; ++j) o[j] *= corr;
                m = s;
            }
            float e = __expf(s - m);
            l += e;
            const uint4* vr = reinterpret_cast<const uint4*>(Vb + (size_t)k * DIM);
            #pragma unroll
            for (int jj = 0; jj < 4; ++jj) {
                uint4 v4 = vr[jj];
                uint32_t vv[4] = {v4.x, v4.y, v4.z, v4.w};
                #pragma unroll
                for (int j2 = 0; j2 < 4; ++j2) {
                    o[jj * 8 + 2 * j2]     = fmaf(e, bflo(vv[j2]), o[jj * 8 + 2 * j2]);
                    o[jj * 8 + 2 * j2 + 1] = fmaf(e, bfhi(vv[j2]), o[jj * 8 + 2 * j2 + 1]);
                }
            }
        }
        float inv = 1.f / fmaxf(l, 1e-9f);
        #pragma unroll
        for (int jj = 0; jj < 4; ++jj) {
            uint4 pk;
            uint32_t pw[4];
            #pragma unroll
            for (int j2 = 0; j2 < 4; ++j2) {
                ushort u0 = f2bf(o[jj * 8 + 2 * j2] * inv);
                ushort u1 = f2bf(o[jj * 8 + 2 * j2 + 1] * inv);
                pw[j2] = (uint32_t)u0 | ((uint32_t)u1 << 16);
            }
            pk.x = pw[0]; pk.y = pw[1]; pk.z = pw[2]; pk.w = pw[3];
            *reinterpret_cast<uint4*>(qrow + jj * 8) = pk;   // attended over Q slot
        }
    }
}

// ---------------------------------------------------------------------------
// K3: MFMA out-projection + fused bias + residual + LayerNorm.
// attended (bf16, in Q slots) @ Wo^T-tile; residual staged to LDS (union)
// after MFMA; LN via 16-lane shfl_xor row reduce matching C/D layout.
// ---------------------------------------------------------------------------
__global__ __launch_bounds__(256) void out_mfma(
    const ushort* __restrict__ qkv,
    const float* __restrict__ x_don, const float* __restrict__ x_acc,
    const ushort* __restrict__ wtg,
    const float* __restrict__ bo, const float* __restrict__ ln_g, const float* __restrict__ ln_b,
    float* __restrict__ out, int N)
{
    __shared__ __align__(16) char smem[69632];
    ushort (*xs)[136] = reinterpret_cast<ushort(*)[136]>(smem);
    ushort (*wt)[136] = reinterpret_cast<ushort(*)[136]>(smem + 34816);
    float  (*res)[132] = reinterpret_cast<float(*)[132]>(smem);    // epilogue reuse

    const int t = threadIdx.x;
    const int lane = t & 63, wid = t >> 6;
    const int r16 = lane & 15, kg = lane >> 4;
    const int r0 = blockIdx.x * 128;                 // row in [0, 2N)
    const ushort* attb = qkv + (r0 < N ? (size_t)0 : (size_t)2 * N * DIM); // slot0 / slot3
    const float* xresb = (r0 < N) ? x_don : x_acc;
    const int rx0 = (r0 < N) ? r0 : r0 - N;

    #pragma unroll
    for (int p = 0; p < 8; ++p) {                    // stage attended bf16
        int lin = (p * 256 + t) * 8;
        int r = lin >> 7, k = lin & 127;
        *reinterpret_cast<uint4*>(&xs[r][k]) =
            *reinterpret_cast<const uint4*>(&attb[(size_t)(r0 + r) * DIM + k]);
    }
    const ushort* wsrc = wtg + ((size_t)3 << 14);    // Wo^T
    #pragma unroll
    for (int p = 0; p < 8; ++p) {
        int lin = (p * 256 + t) * 8;
        int c = lin >> 7, k = lin & 127;
        *reinterpret_cast<uint4*>(&wt[c][k]) =
            *reinterpret_cast<const uint4*>(&wsrc[c * DIM + k]);
    }
    __syncthreads();

    f32x4 acc[2][8];
    #pragma unroll
    for (int i = 0; i < 2; ++i)
        #pragma unroll
        for (int j = 0; j < 8; ++j) acc[i][j] = (f32x4){0.f, 0.f, 0.f, 0.f};

    #pragma unroll
    for (int ks = 0; ks < 4; ++ks) {
        int kb = ks * 32 + kg * 8;
        bf16x8 a0 = *reinterpret_cast<const bf16x8*>(&xs[wid * 32 + r16][kb]);
        bf16x8 a1 = *reinterpret_cast<const bf16x8*>(&xs[wid * 32 + 16 + r16][kb]);
        #pragma unroll
        for (int ct = 0; ct < 8; ++ct) {
            bf16x8 bfr = *reinterpret_cast<const bf16x8*>(&wt[ct * 16 + r16][kb]);
            acc[0][ct] = __builtin_amdgcn_mfma_f32_16x16x32_bf16(a0, bfr, acc[0][ct], 0, 0, 0);
            acc[1][ct] = __builtin_amdgcn_mfma_f32_16x16x32_bf16(a1, bfr, acc[1][ct], 0, 0, 0);
        }
    }
    __syncthreads();                                 // MFMA reads done; reuse LDS

    #pragma unroll
    for (int p = 0; p < 16; ++p) {                   // stage residual fp32
        int lin = (p * 256 + t) * 4;
        int r = lin >> 7, k = lin & 127;
        *reinterpret_cast<float4*>(&res[r][k]) =
            *reinterpret_cast<const float4*>(&xresb[(size_t)(rx0 + r) * DIM + k]);
    }
    __syncthreads();

    float bo8[8], g8[8], be8[8];
    #pragma unroll
    for (int ct = 0; ct < 8; ++ct) {
        int c = ct * 16 + r16;
        bo8[ct] = bo[c]; g8[ct] = ln_g[c]; be8[ct] = ln_b[c];
    }

    #pragma unroll
    for (int rt = 0; rt < 2; ++rt) {
        #pragma unroll
        for (int j = 0; j < 4; ++j) {
            int rl = wid * 32 + rt * 16 + kg * 4 + j;
            float y[8];
            float s = 0.f, ss = 0.f;
            #pragma unroll
            for (int ct = 0; ct < 8; ++ct) {
                float v = acc[rt][ct][j] + bo8[ct] + res[rl][ct * 16 + r16];
                y[ct] = v; s += v; ss += v * v;
            }
            #pragma unroll
            for (int mk2 = 1; mk2 < 16; mk2 <<= 1) {
                s  += __shfl_xor(s, mk2);
                ss += __shfl_xor(ss, mk2);
            }
            float mu   = s * (1.f / 128.f);
            float var  = ss * (1.f / 128.f) - mu * mu;
            float rinv = rsqrtf(var + LN_EPS);
            #pragma unroll
            for (int ct = 0; ct < 8; ++ct)
                out[(size_t)(r0 + rl) * DIM + ct * 16 + r16] =
                    (y[ct] - mu) * rinv * g8[ct] + be8[ct];
        }
    }
}

// ---------------------------------------------------------------------------
extern "C" void kernel_launch(void* const* d_in, const int* in_sizes, int n_in,
                              void* d_out, int out_size, void* d_ws, size_t ws_size,
                              hipStream_t stream)
{
    const float* x_don = (const float*)d_in[0];
    const float* x_acc = (const float*)d_in[1];
    const float* Wq = (const float*)d_in[2];  const float* bq = (const float*)d_in[3];
    const float* Wk = (const float*)d_in[4];  const float* bk = (const float*)d_in[5];
    const float* Wv = (const float*)d_in[6];  const float* bv = (const float*)d_in[7];
    const float* Wo = (const float*)d_in[8];  const float* bo = (const float*)d_in[9];
    const float* ln_g = (const float*)d_in[10]; const float* ln_b = (const float*)d_in[11];
    const int* batch_don = (const int*)d_in[12];
    const int* batch_acc = (const int*)d_in[13];
    const int N = in_sizes[0] / DIM;          // 65536
    float* out = (float*)d_out;

    char* ws = (char*)d_ws;
    int* starts = (int*)ws;                           // 2*NB ints
    int* counts = starts + 2 * NB;                    // 2*NB ints
    ushort* qkv = (ushort*)(ws + 16384);              // 6 x N*DIM bf16 (96MB)
    ushort* wtg = (ushort*)(ws + 16384 + (size_t)6 * N * DIM * 2);  // 4 x 16384 bf16

    seg_kernel<<<8, 256, 0, stream>>>(batch_don, batch_acc, starts, counts, N);
    prep_kernel<<<256, 256, 0, stream>>>(Wq, Wk, Wv, Wo, wtg);

    dim3 gproj(N / 128, 2);
    proj_mfma<<<gproj, 256, 0, stream>>>(x_don, x_acc, wtg, bq, bk, bv, qkv, N);

    dim3 gattn(NB, 2);
    attn_kernel<<<gattn, 256, 0, stream>>>(qkv, starts, counts, N);

    out_mfma<<<(2 * N) / 128, 256, 0, stream>>>(qkv, x_don, x_acc, wtg,
                                                bo, ln_g, ln_b, out, N);
}

// Round 3
// 162.655 us; speedup vs baseline: 3.5934x; 1.7939x over previous
//
#include <hip/hip_runtime.h>
#include <stdint.h>

#define NB 1024          // B molecules
#define LMAX 160
#define DIM 128
#define NH 4
#define HDIM 32
#define ATT_SCALE 0.1767766952966369f   // 32^-0.5
#define LN_EPS 1e-5f
#define VTP 184          // V^T LDS pitch (elems): 16B-aligned rows, balanced banks
#define PSP 40           // P LDS pitch (one 32-k chunk + pad)

typedef __attribute__((ext_vector_type(8))) short bf16x8;
typedef __attribute__((ext_vector_type(4))) float f32x4;

__device__ __forceinline__ float bflo(uint32_t u) { return __uint_as_float(u << 16); }
__device__ __forceinline__ float bfhi(uint32_t u) { return __uint_as_float(u & 0xffff0000u); }
__device__ __forceinline__ ushort f2bf(float f) {
    uint32_t x = __float_as_uint(f);
    x += 0x7fffu + ((x >> 16) & 1u);   // round-to-nearest-even
    return (ushort)(x >> 16);
}

// ---------------------------------------------------------------------------
// K0: segment starts/counts via binary search on the sorted batch arrays.
// ---------------------------------------------------------------------------
__global__ void seg_kernel(const int* __restrict__ bd, const int* __restrict__ ba,
                           int* __restrict__ starts, int* __restrict__ counts, int N)
{
    int t = blockIdx.x * blockDim.x + threadIdx.x;
    if (t >= 2 * NB) return;
    int side = t >> 10;
    int b = t & (NB - 1);
    const int* arr = side ? ba : bd;
    int lo = 0, hi = N;
    while (lo < hi) { int mid = (lo + hi) >> 1; if (arr[mid] < b) lo = mid + 1; else hi = mid; }
    int st = lo;
    hi = N;
    while (lo < hi) { int mid = (lo + hi) >> 1; if (arr[mid] < b + 1) lo = mid + 1; else hi = mid; }
    starts[t] = st;
    counts[t] = lo - st;
}

// ---------------------------------------------------------------------------
// K0b: pre-transpose weights to bf16 [c][k] layout.  m: 0=Wq 1=Wk 2=Wv 3=Wo.
// ---------------------------------------------------------------------------
__global__ void prep_kernel(const float* __restrict__ Wq, const float* __restrict__ Wk,
                            const float* __restrict__ Wv, const float* __restrict__ Wo,
                            ushort* __restrict__ wtg)
{
    int t = blockIdx.x * blockDim.x + threadIdx.x;   // 65536 threads
    int m = t >> 14;
    int idx = t & 16383;
    int k = idx >> 7, c = idx & 127;
    const float* W = (m == 0) ? Wq : (m == 1) ? Wk : (m == 2) ? Wv : Wo;
    wtg[(m << 14) + c * DIM + k] = f2bf(W[idx]);
}

// ---------------------------------------------------------------------------
// K1: MFMA projections.  128x128 tile, K=128, loops Wq/Wk/Wv.
// ---------------------------------------------------------------------------
__global__ __launch_bounds__(256) void proj_mfma(
    const float* __restrict__ x_don, const float* __restrict__ x_acc,
    const ushort* __restrict__ wtg,
    const float* __restrict__ bq, const float* __restrict__ bk, const float* __restrict__ bv,
    ushort* __restrict__ qkv, int N)
{
    __shared__ ushort xs[128][136];
    __shared__ ushort wt[128][136];
    const int side = blockIdx.y;
    const float* x = side ? x_acc : x_don;
    const int r0 = blockIdx.x * 128;
    const int t = threadIdx.x;
    const int lane = t & 63, wid = t >> 6;
    const int r16 = lane & 15, kg = lane >> 4;

    #pragma unroll
    for (int p = 0; p < 16; ++p) {                   // stage x (fp32 -> bf16)
        int lin = (p * 256 + t) * 4;
        int r = lin >> 7, k = lin & 127;
        float4 v = *reinterpret_cast<const float4*>(&x[(size_t)(r0 + r) * DIM + k]);
        uint2 pk;
        pk.x = (uint32_t)f2bf(v.x) | ((uint32_t)f2bf(v.y) << 16);
        pk.y = (uint32_t)f2bf(v.z) | ((uint32_t)f2bf(v.w) << 16);
        *reinterpret_cast<uint2*>(&xs[r][k]) = pk;
    }

    for (int w = 0; w < 3; ++w) {
        __syncthreads();                             // xs ready / prior wt reads done
        const ushort* wsrc = wtg + ((size_t)w << 14);
        #pragma unroll
        for (int p = 0; p < 8; ++p) {
            int lin = (p * 256 + t) * 8;
            int c = lin >> 7, k = lin & 127;
            *reinterpret_cast<uint4*>(&wt[c][k]) =
                *reinterpret_cast<const uint4*>(&wsrc[c * DIM + k]);
        }
        __syncthreads();

        f32x4 acc[2][8];
        #pragma unroll
        for (int i = 0; i < 2; ++i)
            #pragma unroll
            for (int j = 0; j < 8; ++j) acc[i][j] = (f32x4){0.f, 0.f, 0.f, 0.f};

        #pragma unroll
        for (int ks = 0; ks < 4; ++ks) {
            int kb = ks * 32 + kg * 8;
            bf16x8 a0 = *reinterpret_cast<const bf16x8*>(&xs[wid * 32 + r16][kb]);
            bf16x8 a1 = *reinterpret_cast<const bf16x8*>(&xs[wid * 32 + 16 + r16][kb]);
            #pragma unroll
            for (int ct = 0; ct < 8; ++ct) {
                bf16x8 bfr = *reinterpret_cast<const bf16x8*>(&wt[ct * 16 + r16][kb]);
                acc[0][ct] = __builtin_amdgcn_mfma_f32_16x16x32_bf16(a0, bfr, acc[0][ct], 0, 0, 0);
                acc[1][ct] = __builtin_amdgcn_mfma_f32_16x16x32_bf16(a1, bfr, acc[1][ct], 0, 0, 0);
            }
        }

        const float* bias = (w == 0) ? bq : (w == 1) ? bk : bv;
        float b8[8];
        #pragma unroll
        for (int ct = 0; ct < 8; ++ct) b8[ct] = bias[ct * 16 + r16];
        ushort* outp = qkv + (size_t)(side * 3 + w) * N * DIM;
        #pragma unroll
        for (int rt = 0; rt < 2; ++rt)
            #pragma unroll
            for (int ct = 0; ct < 8; ++ct)
                #pragma unroll
                for (int j = 0; j < 4; ++j) {
                    int rr = r0 + wid * 32 + rt * 16 + kg * 4 + j;
                    outp[(size_t)rr * DIM + ct * 16 + r16] = f2bf(acc[rt][ct][j] + b8[ct]);
                }
    }
}

// ---------------------------------------------------------------------------
// K2: MFMA cross attention.  grid (B, 2), 4 waves = 4 heads.
// QK^T: A=Q (global 16B/lane), B-frag straight from row-major K in global
// (L1-served re-reads).  Online softmax per 32-k chunk in C-layout; P goes
// through a per-wave 16x40 LDS tile to become an A-fragment; V staged
// transposed in LDS once per block.  Attended written bf16 over the Q slot.
// LDS 52KB -> 3 blocks/CU.
// ---------------------------------------------------------------------------
__global__ __launch_bounds__(256, 3) void attn_mfma(
    ushort* __restrict__ qkv,
    const int* __restrict__ starts, const int* __restrict__ counts, int N)
{
    __shared__ __align__(16) ushort Vt[128][VTP];      // 47104 B
    __shared__ __align__(16) ushort Ps[4][16][PSP];    //  5120 B
    const int b = blockIdx.x, dir = blockIdx.y;
    const int qside = dir, kside = 1 - dir;
    const int qs = starts[qside * NB + b];
    const int nq = counts[qside * NB + b];
    if (nq == 0) return;
    const int kst = starts[kside * NB + b];
    const int nk = min(counts[kside * NB + b], LMAX);
    ushort* Q = qkv + (size_t)(qside * 3) * N * DIM;
    const ushort* K = qkv + (size_t)(kside * 3 + 1) * N * DIM;
    const ushort* V = qkv + (size_t)(kside * 3 + 2) * N * DIM;
    const int t = threadIdx.x;
    const int lane = t & 63, wid = t >> 6;
    const int r16 = lane & 15, g = lane >> 4;

    const int NCK = (nk + 31) >> 5;     // 32-k chunks
    const int NKP = NCK << 5;

    // ---- stage V^T: lane = k-row (conflict-free u16 writes), wave = d-chunk group
    for (int kr = lane; kr < nk; kr += 64) {
        #pragma unroll
        for (int ii = 0; ii < 4; ++ii) {
            int c = wid * 4 + ii;       // d-chunk 0..15
            uint4 v4 = *reinterpret_cast<const uint4*>(&V[(size_t)(kst + kr) * DIM + c * 8]);
            uint32_t vv[4] = {v4.x, v4.y, v4.z, v4.w};
            #pragma unroll
            for (int j2 = 0; j2 < 4; ++j2) {
                Vt[c * 8 + 2 * j2][kr]     = (ushort)(vv[j2] & 0xffffu);
                Vt[c * 8 + 2 * j2 + 1][kr] = (ushort)(vv[j2] >> 16);
            }
        }
    }
    {   // zero-fill V^T cols [nk, NKP) so masked P (=0) never meets Inf/NaN
        int pad = NKP - nk;
        for (int i = t; i < (pad << 7); i += 256) {
            int d = i & 127, col = nk + (i >> 7);
            Vt[d][col] = 0;
        }
    }
    __syncthreads();

    const int hcol = wid * HDIM;        // this wave's head columns

    for (int q0 = 0; q0 < nq; q0 += 16) {
        bf16x8 aQ = *reinterpret_cast<const bf16x8*>(
            &Q[(size_t)(qs + q0 + r16) * DIM + hcol + g * 8]);

        float m[4], l[4];
        f32x4 oa0 = {0.f, 0.f, 0.f, 0.f}, oa1 = {0.f, 0.f, 0.f, 0.f};
        #pragma unroll
        for (int j = 0; j < 4; ++j) { m[j] = -1e30f; l[j] = 0.f; }

        for (int ck = 0; ck < NCK; ++ck) {
            const int k0 = ck * 32;
            bf16x8 bK0 = *reinterpret_cast<const bf16x8*>(
                &K[(size_t)(kst + k0 + r16) * DIM + hcol + g * 8]);
            bf16x8 bK1 = *reinterpret_cast<const bf16x8*>(
                &K[(size_t)(kst + k0 + 16 + r16) * DIM + hcol + g * 8]);
            f32x4 s0 = __builtin_amdgcn_mfma_f32_16x16x32_bf16(
                aQ, bK0, (f32x4){0.f, 0.f, 0.f, 0.f}, 0, 0, 0);
            f32x4 s1 = __builtin_amdgcn_mfma_f32_16x16x32_bf16(
                aQ, bK1, (f32x4){0.f, 0.f, 0.f, 0.f}, 0, 0, 0);

            const bool v0 = (k0 + r16) < nk, v1 = (k0 + 16 + r16) < nk;
            float p0[4], p1[4], corr[4];
            #pragma unroll
            for (int j = 0; j < 4; ++j) {
                float sv0 = v0 ? s0[j] * ATT_SCALE : -1e30f;
                float sv1 = v1 ? s1[j] * ATT_SCALE : -1e30f;
                float tm = fmaxf(sv0, sv1);
                #pragma unroll
                for (int mk = 1; mk < 16; mk <<= 1) tm = fmaxf(tm, __shfl_xor(tm, mk));
                float mnj = fmaxf(m[j], tm);
                float c  = __expf(m[j] - mnj);
                float e0 = __expf(sv0 - mnj);
                float e1 = __expf(sv1 - mnj);
                float ps = e0 + e1;
                #pragma unroll
                for (int mk = 1; mk < 16; mk <<= 1) ps += __shfl_xor(ps, mk);
                l[j] = l[j] * c + ps;
                m[j] = mnj;
                p0[j] = e0; p1[j] = e1; corr[j] = c;
            }
            #pragma unroll
            for (int j = 0; j < 4; ++j) { oa0[j] *= corr[j]; oa1[j] *= corr[j]; }

            // C-layout -> A-fragment via per-wave LDS tile (same-wave DS ordering)
            #pragma unroll
            for (int j = 0; j < 4; ++j) {
                Ps[wid][g * 4 + j][r16]      = f2bf(p0[j]);
                Ps[wid][g * 4 + j][16 + r16] = f2bf(p1[j]);
            }
            bf16x8 aP  = *reinterpret_cast<const bf16x8*>(&Ps[wid][r16][g * 8]);
            bf16x8 bV0 = *reinterpret_cast<const bf16x8*>(&Vt[hcol + r16][k0 + g * 8]);
            bf16x8 bV1 = *reinterpret_cast<const bf16x8*>(&Vt[hcol + 16 + r16][k0 + g * 8]);
            oa0 = __builtin_amdgcn_mfma_f32_16x16x32_bf16(aP, bV0, oa0, 0, 0, 0);
            oa1 = __builtin_amdgcn_mfma_f32_16x16x32_bf16(aP, bV1, oa1, 0, 0, 0);
        }

        #pragma unroll
        for (int j = 0; j < 4; ++j) {
            int r = q0 + g * 4 + j;
            if (r < nq) {
                float inv = 1.f / fmaxf(l[j], 1e-9f);
                ushort* dst = &Q[(size_t)(qs + r) * DIM + hcol];
                dst[r16]      = f2bf(oa0[j] * inv);
                dst[16 + r16] = f2bf(oa1[j] * inv);
            }
        }
    }
}

// ---------------------------------------------------------------------------
// K3: MFMA out-projection + fused bias + residual + LayerNorm.
// ---------------------------------------------------------------------------
__global__ __launch_bounds__(256) void out_mfma(
    const ushort* __restrict__ qkv,
    const float* __restrict__ x_don, const float* __restrict__ x_acc,
    const ushort* __restrict__ wtg,
    const float* __restrict__ bo, const float* __restrict__ ln_g, const float* __restrict__ ln_b,
    float* __restrict__ out, int N)
{
    __shared__ __align__(16) char smem[69632];
    ushort (*xs)[136] = reinterpret_cast<ushort(*)[136]>(smem);
    ushort (*wt)[136] = reinterpret_cast<ushort(*)[136]>(smem + 34816);
    float  (*res)[132] = reinterpret_cast<float(*)[132]>(smem);    // epilogue reuse

    const int t = threadIdx.x;
    const int lane = t & 63, wid = t >> 6;
    const int r16 = lane & 15, kg = lane >> 4;
    const int r0 = blockIdx.x * 128;                 // row in [0, 2N)
    const ushort* attb = qkv + (r0 < N ? (size_t)0 : (size_t)2 * N * DIM); // slot0/slot3
    const float* xresb = (r0 < N) ? x_don : x_acc;
    const int rx0 = (r0 < N) ? r0 : r0 - N;

    #pragma unroll
    for (int p = 0; p < 8; ++p) {                    // stage attended bf16
        int lin = (p * 256 + t) * 8;
        int r = lin >> 7, k = lin & 127;
        *reinterpret_cast<uint4*>(&xs[r][k]) =
            *reinterpret_cast<const uint4*>(&attb[(size_t)(r0 + r) * DIM + k]);
    }
    const ushort* wsrc = wtg + ((size_t)3 << 14);    // Wo^T
    #pragma unroll
    for (int p = 0; p < 8; ++p) {
        int lin = (p * 256 + t) * 8;
        int c = lin >> 7, k = lin & 127;
        *reinterpret_cast<uint4*>(&wt[c][k]) =
            *reinterpret_cast<const uint4*>(&wsrc[c * DIM + k]);
    }
    __syncthreads();

    f32x4 acc[2][8];
    #pragma unroll
    for (int i = 0; i < 2; ++i)
        #pragma unroll
        for (int j = 0; j < 8; ++j) acc[i][j] = (f32x4){0.f, 0.f, 0.f, 0.f};

    #pragma unroll
    for (int ks = 0; ks < 4; ++ks) {
        int kb = ks * 32 + kg * 8;
        bf16x8 a0 = *reinterpret_cast<const bf16x8*>(&xs[wid * 32 + r16][kb]);
        bf16x8 a1 = *reinterpret_cast<const bf16x8*>(&xs[wid * 32 + 16 + r16][kb]);
        #pragma unroll
        for (int ct = 0; ct < 8; ++ct) {
            bf16x8 bfr = *reinterpret_cast<const bf16x8*>(&wt[ct * 16 + r16][kb]);
            acc[0][ct] = __builtin_amdgcn_mfma_f32_16x16x32_bf16(a0, bfr, acc[0][ct], 0, 0, 0);
            acc[1][ct] = __builtin_amdgcn_mfma_f32_16x16x32_bf16(a1, bfr, acc[1][ct], 0, 0, 0);
        }
    }
    __syncthreads();                                 // MFMA reads done; reuse LDS

    #pragma unroll
    for (int p = 0; p < 16; ++p) {                   // stage residual fp32
        int lin = (p * 256 + t) * 4;
        int r = lin >> 7, k = lin & 127;
        *reinterpret_cast<float4*>(&res[r][k]) =
            *reinterpret_cast<const float4*>(&xresb[(size_t)(rx0 + r) * DIM + k]);
    }
    __syncthreads();

    float bo8[8], g8[8], be8[8];
    #pragma unroll
    for (int ct = 0; ct < 8; ++ct) {
        int c = ct * 16 + r16;
        bo8[ct] = bo[c]; g8[ct] = ln_g[c]; be8[ct] = ln_b[c];
    }

    #pragma unroll
    for (int rt = 0; rt < 2; ++rt) {
        #pragma unroll
        for (int j = 0; j < 4; ++j) {
            int rl = wid * 32 + rt * 16 + kg * 4 + j;
            float y[8];
            float s = 0.f, ss = 0.f;
            #pragma unroll
            for (int ct = 0; ct < 8; ++ct) {
                float v = acc[rt][ct][j] + bo8[ct] + res[rl][ct * 16 + r16];
                y[ct] = v; s += v; ss += v * v;
            }
            #pragma unroll
            for (int mk2 = 1; mk2 < 16; mk2 <<= 1) {
                s  += __shfl_xor(s, mk2);
                ss += __shfl_xor(ss, mk2);
            }
            float mu   = s * (1.f / 128.f);
            float var  = ss * (1.f / 128.f) - mu * mu;
            float rinv = rsqrtf(var + LN_EPS);
            #pragma unroll
            for (int ct = 0; ct < 8; ++ct)
                out[(size_t)(r0 + rl) * DIM + ct * 16 + r16] =
                    (y[ct] - mu) * rinv * g8[ct] + be8[ct];
        }
    }
}

// ---------------------------------------------------------------------------
extern "C" void kernel_launch(void* const* d_in, const int* in_sizes, int n_in,
                              void* d_out, int out_size, void* d_ws, size_t ws_size,
                              hipStream_t stream)
{
    const float* x_don = (const float*)d_in[0];
    const float* x_acc = (const float*)d_in[1];
    const float* Wq = (const float*)d_in[2];  const float* bq = (const float*)d_in[3];
    const float* Wk = (const float*)d_in[4];  const float* bk = (const float*)d_in[5];
    const float* Wv = (const float*)d_in[6];  const float* bv = (const float*)d_in[7];
    const float* Wo = (const float*)d_in[8];  const float* bo = (const float*)d_in[9];
    const float* ln_g = (const float*)d_in[10]; const float* ln_b = (const float*)d_in[11];
    const int* batch_don = (const int*)d_in[12];
    const int* batch_acc = (const int*)d_in[13];
    const int N = in_sizes[0] / DIM;          // 65536
    float* out = (float*)d_out;

    char* ws = (char*)d_ws;
    int* starts = (int*)ws;                           // 2*NB ints
    int* counts = starts + 2 * NB;                    // 2*NB ints
    ushort* qkv = (ushort*)(ws + 16384);              // 6 x N*DIM bf16 (96MB)
    ushort* wtg = (ushort*)(ws + 16384 + (size_t)6 * N * DIM * 2);  // 4 x 16384 bf16

    seg_kernel<<<8, 256, 0, stream>>>(batch_don, batch_acc, starts, counts, N);
    prep_kernel<<<256, 256, 0, stream>>>(Wq, Wk, Wv, Wo, wtg);

    dim3 gproj(N / 128, 2);
    proj_mfma<<<gproj, 256, 0, stream>>>(x_don, x_acc, wtg, bq, bk, bv, qkv, N);

    dim3 gattn(NB, 2);
    attn_mfma<<<gattn, 256, 0, stream>>>(qkv, starts, counts, N);

    out_mfma<<<(2 * N) / 128, 256, 0, stream>>>(qkv, x_don, x_acc, wtg,
                                                bo, ln_g, ln_b, out, N);
}

// Round 4
// 145.679 us; speedup vs baseline: 4.0121x; 1.1165x over previous
//
#include <hip/hip_runtime.h>
#include <stdint.h>

#define NB 1024          // B molecules
#define LMAX 160
#define DIM 128
#define NH 4
#define HDIM 32
#define ATT_SCALE 0.1767766952966369f   // 32^-0.5
#define LN_EPS 1e-5f
#define VTP 164          // V^T LDS pitch (u16): 82 dwords, 82%32=18, gcd(18,32)=2 -> conflict-free b64 reads
#define PSP 40           // P LDS pitch (u16): 80B rows, 16B-aligned for b128

typedef __attribute__((ext_vector_type(8))) short bf16x8;
typedef __attribute__((ext_vector_type(4))) float f32x4;

union U8 { uint2 u[2]; bf16x8 v; };

__device__ __forceinline__ ushort f2bf(float f) {
    uint32_t x = __float_as_uint(f);
    x += 0x7fffu + ((x >> 16) & 1u);   // round-to-nearest-even
    return (ushort)(x >> 16);
}

// ---------------------------------------------------------------------------
// K0: segment starts/counts via binary search on the sorted batch arrays.
// ---------------------------------------------------------------------------
__global__ void seg_kernel(const int* __restrict__ bd, const int* __restrict__ ba,
                           int* __restrict__ starts, int* __restrict__ counts, int N)
{
    int t = blockIdx.x * blockDim.x + threadIdx.x;
    if (t >= 2 * NB) return;
    int side = t >> 10;
    int b = t & (NB - 1);
    const int* arr = side ? ba : bd;
    int lo = 0, hi = N;
    while (lo < hi) { int mid = (lo + hi) >> 1; if (arr[mid] < b) lo = mid + 1; else hi = mid; }
    int st = lo;
    hi = N;
    while (lo < hi) { int mid = (lo + hi) >> 1; if (arr[mid] < b + 1) lo = mid + 1; else hi = mid; }
    starts[t] = st;
    counts[t] = lo - st;
}

// ---------------------------------------------------------------------------
// K0b: pre-transpose weights to bf16 [c][k] layout.  m: 0=Wq 1=Wk 2=Wv 3=Wo.
// ---------------------------------------------------------------------------
__global__ void prep_kernel(const float* __restrict__ Wq, const float* __restrict__ Wk,
                            const float* __restrict__ Wv, const float* __restrict__ Wo,
                            ushort* __restrict__ wtg)
{
    int t = blockIdx.x * blockDim.x + threadIdx.x;   // 65536 threads
    int m = t >> 14;
    int idx = t & 16383;
    int k = idx >> 7, c = idx & 127;
    const float* W = (m == 0) ? Wq : (m == 1) ? Wk : (m == 2) ? Wv : Wo;
    wtg[(m << 14) + c * DIM + k] = f2bf(W[idx]);
}

// ---------------------------------------------------------------------------
// K1: MFMA projections.  128x128 tile, K=128, loops Wq/Wk/Wv.
// ---------------------------------------------------------------------------
__global__ __launch_bounds__(256) void proj_mfma(
    const float* __restrict__ x_don, const float* __restrict__ x_acc,
    const ushort* __restrict__ wtg,
    const float* __restrict__ bq, const float* __restrict__ bk, const float* __restrict__ bv,
    ushort* __restrict__ qkv, int N)
{
    __shared__ ushort xs[128][136];
    __shared__ ushort wt[128][136];
    const int side = blockIdx.y;
    const float* x = side ? x_acc : x_don;
    const int r0 = blockIdx.x * 128;
    const int t = threadIdx.x;
    const int lane = t & 63, wid = t >> 6;
    const int r16 = lane & 15, kg = lane >> 4;

    #pragma unroll
    for (int p = 0; p < 16; ++p) {                   // stage x (fp32 -> bf16)
        int lin = (p * 256 + t) * 4;
        int r = lin >> 7, k = lin & 127;
        float4 v = *reinterpret_cast<const float4*>(&x[(size_t)(r0 + r) * DIM + k]);
        uint2 pk;
        pk.x = (uint32_t)f2bf(v.x) | ((uint32_t)f2bf(v.y) << 16);
        pk.y = (uint32_t)f2bf(v.z) | ((uint32_t)f2bf(v.w) << 16);
        *reinterpret_cast<uint2*>(&xs[r][k]) = pk;
    }

    for (int w = 0; w < 3; ++w) {
        __syncthreads();                             // xs ready / prior wt reads done
        const ushort* wsrc = wtg + ((size_t)w << 14);
        #pragma unroll
        for (int p = 0; p < 8; ++p) {
            int lin = (p * 256 + t) * 8;
            int c = lin >> 7, k = lin & 127;
            *reinterpret_cast<uint4*>(&wt[c][k]) =
                *reinterpret_cast<const uint4*>(&wsrc[c * DIM + k]);
        }
        __syncthreads();

        f32x4 acc[2][8];
        #pragma unroll
        for (int i = 0; i < 2; ++i)
            #pragma unroll
            for (int j = 0; j < 8; ++j) acc[i][j] = (f32x4){0.f, 0.f, 0.f, 0.f};

        #pragma unroll
        for (int ks = 0; ks < 4; ++ks) {
            int kb = ks * 32 + kg * 8;
            bf16x8 a0 = *reinterpret_cast<const bf16x8*>(&xs[wid * 32 + r16][kb]);
            bf16x8 a1 = *reinterpret_cast<const bf16x8*>(&xs[wid * 32 + 16 + r16][kb]);
            #pragma unroll
            for (int ct = 0; ct < 8; ++ct) {
                bf16x8 bfr = *reinterpret_cast<const bf16x8*>(&wt[ct * 16 + r16][kb]);
                acc[0][ct] = __builtin_amdgcn_mfma_f32_16x16x32_bf16(a0, bfr, acc[0][ct], 0, 0, 0);
                acc[1][ct] = __builtin_amdgcn_mfma_f32_16x16x32_bf16(a1, bfr, acc[1][ct], 0, 0, 0);
            }
        }

        const float* bias = (w == 0) ? bq : (w == 1) ? bk : bv;
        float b8[8];
        #pragma unroll
        for (int ct = 0; ct < 8; ++ct) b8[ct] = bias[ct * 16 + r16];
        ushort* outp = qkv + (size_t)(side * 3 + w) * N * DIM;
        #pragma unroll
        for (int rt = 0; rt < 2; ++rt)
            #pragma unroll
            for (int ct = 0; ct < 8; ++ct)
                #pragma unroll
                for (int j = 0; j < 4; ++j) {
                    int rr = r0 + wid * 32 + rt * 16 + kg * 4 + j;
                    outp[(size_t)rr * DIM + ct * 16 + r16] = f2bf(acc[rt][ct][j] + b8[ct]);
                }
    }
}

// ---------------------------------------------------------------------------
// K2: swapped-operand MFMA cross attention.  grid (B, 2, NH), 1 wave = 1 head.
// QK^T swapped: S^T = mfma(A=K rows, B=Q^T) -> lane holds 8 k-scores for ONE
// q (col=lane&15).  Online softmax lane-local (2 shfl per chunk).  PV swapped:
// O^T = mfma(A=V^T from LDS, B=P^T from tiny LDS tile) -> accumulator also
// q-in-lane, so corr and 1/l need no cross-lane traffic.  Attended written
// bf16 over the Q slot.  LDS ~11.8KB, barrier-free (single wave).
// ---------------------------------------------------------------------------
__global__ __launch_bounds__(64, 4) void attn_mfma(
    ushort* __restrict__ qkv,
    const int* __restrict__ starts, const int* __restrict__ counts, int N)
{
    __shared__ __align__(16) ushort Vt[HDIM][VTP];   // V^T slice for this head
    __shared__ __align__(16) ushort Ps[16][PSP];     // P round-trip tile
    const int b = blockIdx.x, dir = blockIdx.y;
    const int hcol = blockIdx.z * HDIM;
    const int qside = dir, kside = 1 - dir;
    const int qs = starts[qside * NB + b];
    const int nq = counts[qside * NB + b];
    if (nq == 0) return;
    const int kst = starts[kside * NB + b];
    const int nk = min(counts[kside * NB + b], LMAX);
    ushort* Q = qkv + (size_t)(qside * 3) * N * DIM;
    const ushort* K = qkv + (size_t)(kside * 3 + 1) * N * DIM;
    const ushort* V = qkv + (size_t)(kside * 3 + 2) * N * DIM;
    const int lane = threadIdx.x;
    const int r16 = lane & 15, g = lane >> 4;

    const int NCK = (nk + 31) >> 5;
    const int NKP = NCK << 5;

    // ---- stage V^T slice: lane (kr=lane>>2, c=lane&3) reads 16B of a V row,
    //      scatters 8 u16 down column kr.
    {
        const int krl = lane >> 2, c = lane & 3;
        for (int base = 0; base < nk; base += 16) {
            int kr = base + krl;
            if (kr < nk) {
                uint4 v4 = *reinterpret_cast<const uint4*>(
                    &V[(size_t)(kst + kr) * DIM + hcol + c * 8]);
                uint32_t vv[4] = {v4.x, v4.y, v4.z, v4.w};
                #pragma unroll
                for (int m2 = 0; m2 < 4; ++m2) {
                    Vt[c * 8 + 2 * m2][kr]     = (ushort)(vv[m2] & 0xffffu);
                    Vt[c * 8 + 2 * m2 + 1][kr] = (ushort)(vv[m2] >> 16);
                }
            }
        }
        int pad = NKP - nk;
        for (int i = lane; i < (pad << 5); i += 64) {
            int d = i & 31, col = nk + (i >> 5);
            Vt[d][col] = 0;
        }
    }
    __syncthreads();   // single wave: compiles to a waitcnt

    for (int q0 = 0; q0 < nq; q0 += 16) {
        const int rq = qs + min(q0 + r16, nq - 1);
        bf16x8 bQ = *reinterpret_cast<const bf16x8*>(&Q[(size_t)rq * DIM + hcol + g * 8]);

        float m = -1e30f, l = 0.f;
        f32x4 oa0 = {0.f, 0.f, 0.f, 0.f}, oa1 = {0.f, 0.f, 0.f, 0.f};

        for (int ck = 0; ck < NCK; ++ck) {
            const int k0 = ck * 32;
            const int rk0 = kst + min(k0 + r16, nk - 1);
            const int rk1 = kst + min(k0 + 16 + r16, nk - 1);
            bf16x8 aK0 = *reinterpret_cast<const bf16x8*>(&K[(size_t)rk0 * DIM + hcol + g * 8]);
            bf16x8 aK1 = *reinterpret_cast<const bf16x8*>(&K[(size_t)rk1 * DIM + hcol + g * 8]);
            f32x4 s0 = __builtin_amdgcn_mfma_f32_16x16x32_bf16(
                aK0, bQ, (f32x4){0.f, 0.f, 0.f, 0.f}, 0, 0, 0);
            f32x4 s1 = __builtin_amdgcn_mfma_f32_16x16x32_bf16(
                aK1, bQ, (f32x4){0.f, 0.f, 0.f, 0.f}, 0, 0, 0);

            // lane holds S[k][q=r16]: s0 -> k=k0+4g+j, s1 -> k=k0+16+4g+j
            float sv[8];
            #pragma unroll
            for (int j = 0; j < 4; ++j) {
                sv[j]     = (k0 + 4 * g + j < nk)      ? s0[j] * ATT_SCALE : -1e30f;
                sv[4 + j] = (k0 + 16 + 4 * g + j < nk) ? s1[j] * ATT_SCALE : -1e30f;
            }
            float tm = fmaxf(fmaxf(fmaxf(sv[0], sv[1]), fmaxf(sv[2], sv[3])),
                             fmaxf(fmaxf(sv[4], sv[5]), fmaxf(sv[6], sv[7])));
            tm = fmaxf(tm, __shfl_xor(tm, 16));
            tm = fmaxf(tm, __shfl_xor(tm, 32));

            bool up = tm > m + 8.f;                  // defer-max (T13)
            float mn = up ? tm : m;
            float corr = up ? __expf(m - tm) : 1.f;

            float e[8];
            #pragma unroll
            for (int j = 0; j < 8; ++j) e[j] = __expf(sv[j] - mn);
            float ps = ((e[0] + e[1]) + (e[2] + e[3])) + ((e[4] + e[5]) + (e[6] + e[7]));
            ps += __shfl_xor(ps, 16);
            ps += __shfl_xor(ps, 32);
            l = l * corr + ps;
            m = mn;
            #pragma unroll
            for (int j = 0; j < 4; ++j) { oa0[j] *= corr; oa1[j] *= corr; }

            // P^T -> B-frag via tiny LDS tile (lane-local k quads -> 2x 8B writes)
            uint2 w0, w1;
            w0.x = (uint32_t)f2bf(e[0]) | ((uint32_t)f2bf(e[1]) << 16);
            w0.y = (uint32_t)f2bf(e[2]) | ((uint32_t)f2bf(e[3]) << 16);
            w1.x = (uint32_t)f2bf(e[4]) | ((uint32_t)f2bf(e[5]) << 16);
            w1.y = (uint32_t)f2bf(e[6]) | ((uint32_t)f2bf(e[7]) << 16);
            *reinterpret_cast<uint2*>(&Ps[r16][4 * g]) = w0;
            *reinterpret_cast<uint2*>(&Ps[r16][16 + 4 * g]) = w1;
            bf16x8 bP = *reinterpret_cast<const bf16x8*>(&Ps[r16][g * 8]);

            U8 av0, av1;   // V^T rows d=r16 / 16+r16, conflict-free b64 pairs
            av0.u[0] = *reinterpret_cast<const uint2*>(&Vt[r16][k0 + g * 8]);
            av0.u[1] = *reinterpret_cast<const uint2*>(&Vt[r16][k0 + g * 8 + 4]);
            av1.u[0] = *reinterpret_cast<const uint2*>(&Vt[16 + r16][k0 + g * 8]);
            av1.u[1] = *reinterpret_cast<const uint2*>(&Vt[16 + r16][k0 + g * 8 + 4]);
            oa0 = __builtin_amdgcn_mfma_f32_16x16x32_bf16(av0.v, bP, oa0, 0, 0, 0);
            oa1 = __builtin_amdgcn_mfma_f32_16x16x32_bf16(av1.v, bP, oa1, 0, 0, 0);
        }

        // O^T layout: col=q=r16 (lane-local l), row d = 4g+j (+16 for oa1)
        if (q0 + r16 < nq) {
            float inv = 1.f / fmaxf(l, 1e-9f);
            ushort* dst = &Q[(size_t)(qs + q0 + r16) * DIM + hcol];
            uint2 o0, o1;
            o0.x = (uint32_t)f2bf(oa0[0] * inv) | ((uint32_t)f2bf(oa0[1] * inv) << 16);
            o0.y = (uint32_t)f2bf(oa0[2] * inv) | ((uint32_t)f2bf(oa0[3] * inv) << 16);
            o1.x = (uint32_t)f2bf(oa1[0] * inv) | ((uint32_t)f2bf(oa1[1] * inv) << 16);
            o1.y = (uint32_t)f2bf(oa1[2] * inv) | ((uint32_t)f2bf(oa1[3] * inv) << 16);
            *reinterpret_cast<uint2*>(dst + 4 * g) = o0;
            *reinterpret_cast<uint2*>(dst + 16 + 4 * g) = o1;
        }
    }
}

// ---------------------------------------------------------------------------
// K3: MFMA out-projection + fused bias + residual + LayerNorm.
// ---------------------------------------------------------------------------
__global__ __launch_bounds__(256) void out_mfma(
    const ushort* __restrict__ qkv,
    const float* __restrict__ x_don, const float* __restrict__ x_acc,
    const ushort* __restrict__ wtg,
    const float* __restrict__ bo, const float* __restrict__ ln_g, const float* __restrict__ ln_b,
    float* __restrict__ out, int N)
{
    __shared__ __align__(16) char smem[69632];
    ushort (*xs)[136] = reinterpret_cast<ushort(*)[136]>(smem);
    ushort (*wt)[136] = reinterpret_cast<ushort(*)[136]>(smem + 34816);
    float  (*res)[132] = reinterpret_cast<float(*)[132]>(smem);    // epilogue reuse

    const int t = threadIdx.x;
    const int lane = t & 63, wid = t >> 6;
    const int r16 = lane & 15, kg = lane >> 4;
    const int r0 = blockIdx.x * 128;                 // row in [0, 2N)
    const ushort* attb = qkv + (r0 < N ? (size_t)0 : (size_t)2 * N * DIM); // slot0/slot3
    const float* xresb = (r0 < N) ? x_don : x_acc;
    const int rx0 = (r0 < N) ? r0 : r0 - N;

    #pragma unroll
    for (int p = 0; p < 8; ++p) {                    // stage attended bf16
        int lin = (p * 256 + t) * 8;
        int r = lin >> 7, k = lin & 127;
        *reinterpret_cast<uint4*>(&xs[r][k]) =
            *reinterpret_cast<const uint4*>(&attb[(size_t)(r0 + r) * DIM + k]);
    }
    const ushort* wsrc = wtg + ((size_t)3 << 14);    // Wo^T
    #pragma unroll
    for (int p = 0; p < 8; ++p) {
        int lin = (p * 256 + t) * 8;
        int c = lin >> 7, k = lin & 127;
        *reinterpret_cast<uint4*>(&wt[c][k]) =
            *reinterpret_cast<const uint4*>(&wsrc[c * DIM + k]);
    }
    __syncthreads();

    f32x4 acc[2][8];
    #pragma unroll
    for (int i = 0; i < 2; ++i)
        #pragma unroll
        for (int j = 0; j < 8; ++j) acc[i][j] = (f32x4){0.f, 0.f, 0.f, 0.f};

    #pragma unroll
    for (int ks = 0; ks < 4; ++ks) {
        int kb = ks * 32 + kg * 8;
        bf16x8 a0 = *reinterpret_cast<const bf16x8*>(&xs[wid * 32 + r16][kb]);
        bf16x8 a1 = *reinterpret_cast<const bf16x8*>(&xs[wid * 32 + 16 + r16][kb]);
        #pragma unroll
        for (int ct = 0; ct < 8; ++ct) {
            bf16x8 bfr = *reinterpret_cast<const bf16x8*>(&wt[ct * 16 + r16][kb]);
            acc[0][ct] = __builtin_amdgcn_mfma_f32_16x16x32_bf16(a0, bfr, acc[0][ct], 0, 0, 0);
            acc[1][ct] = __builtin_amdgcn_mfma_f32_16x16x32_bf16(a1, bfr, acc[1][ct], 0, 0, 0);
        }
    }
    __syncthreads();                                 // MFMA reads done; reuse LDS

    #pragma unroll
    for (int p = 0; p < 16; ++p) {                   // stage residual fp32
        int lin = (p * 256 + t) * 4;
        int r = lin >> 7, k = lin & 127;
        *reinterpret_cast<float4*>(&res[r][k]) =
            *reinterpret_cast<const float4*>(&xresb[(size_t)(rx0 + r) * DIM + k]);
    }
    __syncthreads();

    float bo8[8], g8[8], be8[8];
    #pragma unroll
    for (int ct = 0; ct < 8; ++ct) {
        int c = ct * 16 + r16;
        bo8[ct] = bo[c]; g8[ct] = ln_g[c]; be8[ct] = ln_b[c];
    }

    #pragma unroll
    for (int rt = 0; rt < 2; ++rt) {
        #pragma unroll
        for (int j = 0; j < 4; ++j) {
            int rl = wid * 32 + rt * 16 + kg * 4 + j;
            float y[8];
            float s = 0.f, ss = 0.f;
            #pragma unroll
            for (int ct = 0; ct < 8; ++ct) {
                float v = acc[rt][ct][j] + bo8[ct] + res[rl][ct * 16 + r16];
                y[ct] = v; s += v; ss += v * v;
            }
            #pragma unroll
            for (int mk2 = 1; mk2 < 16; mk2 <<= 1) {
                s  += __shfl_xor(s, mk2);
                ss += __shfl_xor(ss, mk2);
            }
            float mu   = s * (1.f / 128.f);
            float var  = ss * (1.f / 128.f) - mu * mu;
            float rinv = rsqrtf(var + LN_EPS);
            #pragma unroll
            for (int ct = 0; ct < 8; ++ct)
                out[(size_t)(r0 + rl) * DIM + ct * 16 + r16] =
                    (y[ct] - mu) * rinv * g8[ct] + be8[ct];
        }
    }
}

// ---------------------------------------------------------------------------
extern "C" void kernel_launch(void* const* d_in, const int* in_sizes, int n_in,
                              void* d_out, int out_size, void* d_ws, size_t ws_size,
                              hipStream_t stream)
{
    const float* x_don = (const float*)d_in[0];
    const float* x_acc = (const float*)d_in[1];
    const float* Wq = (const float*)d_in[2];  const float* bq = (const float*)d_in[3];
    const float* Wk = (const float*)d_in[4];  const float* bk = (const float*)d_in[5];
    const float* Wv = (const float*)d_in[6];  const float* bv = (const float*)d_in[7];
    const float* Wo = (const float*)d_in[8];  const float* bo = (const float*)d_in[9];
    const float* ln_g = (const float*)d_in[10]; const float* ln_b = (const float*)d_in[11];
    const int* batch_don = (const int*)d_in[12];
    const int* batch_acc = (const int*)d_in[13];
    const int N = in_sizes[0] / DIM;          // 65536
    float* out = (float*)d_out;

    char* ws = (char*)d_ws;
    int* starts = (int*)ws;                           // 2*NB ints
    int* counts = starts + 2 * NB;                    // 2*NB ints
    ushort* qkv = (ushort*)(ws + 16384);              // 6 x N*DIM bf16 (96MB)
    ushort* wtg = (ushort*)(ws + 16384 + (size_t)6 * N * DIM * 2);  // 4 x 16384 bf16

    seg_kernel<<<8, 256, 0, stream>>>(batch_don, batch_acc, starts, counts, N);
    prep_kernel<<<256, 256, 0, stream>>>(Wq, Wk, Wv, Wo, wtg);

    dim3 gproj(N / 128, 2);
    proj_mfma<<<gproj, 256, 0, stream>>>(x_don, x_acc, wtg, bq, bk, bv, qkv, N);

    dim3 gattn(NB, 2, NH);
    attn_mfma<<<gattn, 64, 0, stream>>>(qkv, starts, counts, N);

    out_mfma<<<(2 * N) / 128, 256, 0, stream>>>(qkv, x_don, x_acc, wtg,
                                                bo, ln_g, ln_b, out, N);
}